// Round 2
// baseline (310.320 us; speedup 1.0000x reference)
//
#include <hip/hip_runtime.h>
#include <cmath>

// BertEmbeddings: B=8, S=2048, H=768. fp32 in/out.
// One 64-lane wave per token; 4 tokens per 256-thread block.
// R1: sinf -> __sinf (hw v_sin, cuts VALU ~5x and VGPR pressure from the
//     Payne-Hanek path); __launch_bounds__(256,6) to force >=6 waves/SIMD.
static constexpr int B_ = 8;
static constexpr int S_ = 2048;
static constexpr int H_ = 768;            // 192 float4 chunks per row
static constexpr int TOKENS = B_ * S_;    // 16384
static constexpr float LN_EPS = 1e-12f;

__global__ __launch_bounds__(256, 6) void bert_emb_kernel(
    const int* __restrict__ word_ids,
    const int* __restrict__ modal_ids,
    const int* __restrict__ seg_ids,
    const int* __restrict__ npi_ids,
    const int* __restrict__ posi_ids,
    const float* __restrict__ age_tau,
    const float* __restrict__ delay_tau,
    const float* __restrict__ word_table,
    const float* __restrict__ modal_table,
    const float* __restrict__ seg_table,
    const float* __restrict__ npi_table,
    const float* __restrict__ posi_table,
    const float* __restrict__ age_w,      // [767]
    const float* __restrict__ age_b,      // [767]
    const float* __restrict__ age_w0,     // [1]
    const float* __restrict__ age_b0,     // [1]
    const float* __restrict__ delay_w,    // [767]
    const float* __restrict__ delay_b,    // [767]
    const float* __restrict__ delay_w0,   // [1]
    const float* __restrict__ delay_b0,   // [1]
    const float* __restrict__ ln_gamma,   // [768]
    const float* __restrict__ ln_beta,    // [768]
    float* __restrict__ out)
{
    const int wave = threadIdx.x >> 6;         // 0..3
    const int lane = threadIdx.x & 63;         // 0..63
    const int token = (blockIdx.x << 2) + wave;  // grid = TOKENS/4 exactly

    // Per-token scalars (broadcast loads within the wave)
    const int wid = word_ids[token];
    const int mid = modal_ids[token];
    const int sid = seg_ids[token];
    const int nid = npi_ids[token];
    const int pid = posi_ids[token];
    const float atau = age_tau[token];
    const float dtau = delay_tau[token];
    const float aw0 = age_w0[0], ab0 = age_b0[0];
    const float dw0 = delay_w0[0], db0 = delay_b0[0];

    const float4* wrow = reinterpret_cast<const float4*>(word_table  + (size_t)wid * H_);
    const float4* mrow = reinterpret_cast<const float4*>(modal_table + (size_t)mid * H_);
    const float4* srow = reinterpret_cast<const float4*>(seg_table   + (size_t)sid * H_);
    const float4* nrow = reinterpret_cast<const float4*>(npi_table   + (size_t)nid * H_);
    const float4* prow = reinterpret_cast<const float4*>(posi_table  + (size_t)pid * H_);
    const float4* awv = reinterpret_cast<const float4*>(age_w);
    const float4* abv = reinterpret_cast<const float4*>(age_b);
    const float4* dwv = reinterpret_cast<const float4*>(delay_w);
    const float4* dbv = reinterpret_cast<const float4*>(delay_b);

    float vals[12];
    float ssum = 0.0f, ssq = 0.0f;

#pragma unroll
    for (int c = 0; c < 3; ++c) {
        const int h4 = lane + (c << 6);        // 0..191 (chunk index)
        const float4 we = wrow[h4];
        const float4 me = mrow[h4];
        const float4 se = srow[h4];
        const float4 ne = nrow[h4];
        const float4 pe = prow[h4];

        float4 aw, ab, dw, db;
        if (h4 < (H_ / 4 - 1)) {               // chunks 0..190: fully inside [0,767)
            aw = awv[h4]; ab = abv[h4]; dw = dwv[h4]; db = dbv[h4];
        } else {                               // chunk 191 covers h=764..767; w/b have 767 elems
            aw = make_float4(age_w[764],   age_w[765],   age_w[766],   0.0f);
            ab = make_float4(age_b[764],   age_b[765],   age_b[766],   0.0f);
            dw = make_float4(delay_w[764], delay_w[765], delay_w[766], 0.0f);
            db = make_float4(delay_b[764], delay_b[765], delay_b[766], 0.0f);
        }

        float av0 = __sinf(atau * aw.x + ab.x);
        float av1 = __sinf(atau * aw.y + ab.y);
        float av2 = __sinf(atau * aw.z + ab.z);
        float av3 = __sinf(atau * aw.w + ab.w);
        float dv0 = __sinf(dtau * dw.x + db.x);
        float dv1 = __sinf(dtau * dw.y + db.y);
        float dv2 = __sinf(dtau * dw.z + db.z);
        float dv3 = __sinf(dtau * dw.w + db.w);
        if (h4 == (H_ / 4 - 1)) {              // h = 767: linear branch of time2vec
            av3 = atau * aw0 + ab0;
            dv3 = dtau * dw0 + db0;
        }

        const float e0 = we.x + me.x + se.x + ne.x + pe.x + av0 + dv0;
        const float e1 = we.y + me.y + se.y + ne.y + pe.y + av1 + dv1;
        const float e2 = we.z + me.z + se.z + ne.z + pe.z + av2 + dv2;
        const float e3 = we.w + me.w + se.w + ne.w + pe.w + av3 + dv3;

        vals[c * 4 + 0] = e0;
        vals[c * 4 + 1] = e1;
        vals[c * 4 + 2] = e2;
        vals[c * 4 + 3] = e3;
        ssum += e0 + e1 + e2 + e3;
        ssq  += e0 * e0 + e1 * e1 + e2 * e2 + e3 * e3;
    }

    // Wave-wide (64-lane) reduction for mean / variance
#pragma unroll
    for (int off = 32; off > 0; off >>= 1) {
        ssum += __shfl_down(ssum, off);
        ssq  += __shfl_down(ssq,  off);
    }
    ssum = __shfl(ssum, 0);
    ssq  = __shfl(ssq,  0);

    const float inv_h = 1.0f / (float)H_;
    const float mu = ssum * inv_h;
    const float var = ssq * inv_h - mu * mu;
    const float rstd = rsqrtf(var + LN_EPS);

    const float4* gv = reinterpret_cast<const float4*>(ln_gamma);
    const float4* bv = reinterpret_cast<const float4*>(ln_beta);
    float4* orow = reinterpret_cast<float4*>(out + (size_t)token * H_);

#pragma unroll
    for (int c = 0; c < 3; ++c) {
        const int h4 = lane + (c << 6);
        const float4 g  = gv[h4];
        const float4 bt = bv[h4];
        float4 o;
        o.x = (vals[c * 4 + 0] - mu) * rstd * g.x + bt.x;
        o.y = (vals[c * 4 + 1] - mu) * rstd * g.y + bt.y;
        o.z = (vals[c * 4 + 2] - mu) * rstd * g.z + bt.z;
        o.w = (vals[c * 4 + 3] - mu) * rstd * g.w + bt.w;
        orow[h4] = o;
    }
}

extern "C" void kernel_launch(void* const* d_in, const int* in_sizes, int n_in,
                              void* d_out, int out_size, void* d_ws, size_t ws_size,
                              hipStream_t stream) {
    const int*   word_ids    = (const int*)  d_in[0];
    const int*   modal_ids   = (const int*)  d_in[1];
    const int*   seg_ids     = (const int*)  d_in[2];
    const int*   npi_ids     = (const int*)  d_in[3];
    const int*   posi_ids    = (const int*)  d_in[4];
    const float* age_tau     = (const float*)d_in[5];
    const float* delay_tau   = (const float*)d_in[6];
    const float* word_table  = (const float*)d_in[7];
    const float* modal_table = (const float*)d_in[8];
    const float* seg_table   = (const float*)d_in[9];
    const float* npi_table   = (const float*)d_in[10];
    const float* posi_table  = (const float*)d_in[11];
    const float* age_w       = (const float*)d_in[12];
    const float* age_b       = (const float*)d_in[13];
    const float* age_w0      = (const float*)d_in[14];
    const float* age_b0      = (const float*)d_in[15];
    const float* delay_w     = (const float*)d_in[16];
    const float* delay_b     = (const float*)d_in[17];
    const float* delay_w0    = (const float*)d_in[18];
    const float* delay_b0    = (const float*)d_in[19];
    const float* ln_gamma    = (const float*)d_in[20];
    const float* ln_beta     = (const float*)d_in[21];
    float* out = (float*)d_out;

    dim3 grid(TOKENS / 4);   // 4096 blocks, 4 tokens (waves) each
    dim3 block(256);
    hipLaunchKernelGGL(bert_emb_kernel, grid, block, 0, stream,
                       word_ids, modal_ids, seg_ids, npi_ids, posi_ids,
                       age_tau, delay_tau,
                       word_table, modal_table, seg_table, npi_table, posi_table,
                       age_w, age_b, age_w0, age_b0,
                       delay_w, delay_b, delay_w0, delay_b0,
                       ln_gamma, ln_beta, out);
}

// Round 4
// 236.794 us; speedup vs baseline: 1.3105x; 1.3105x over previous
//
#include <hip/hip_runtime.h>
#include <cmath>

// BertEmbeddings: B=8, S=2048, H=768. fp32 in/out.
// One 64-lane wave per token; 4 tokens per 256-thread block.
// R1 post-mortem: __launch_bounds__(256,6) capped VGPR at ~84 < natural ~110
//   -> massive scratch spills (WRITE 49->246 MB). Natural live set is the
//   15 gather float4s + 12 t2v float4s in flight, NOT sinf.
// R2/R3: keep __sinf; launch_bounds(256,4) (128-VGPR cap, no spill);
//   non-temporal output stores via native ext_vector_type (HIP float4 class
//   is rejected by __builtin_nontemporal_store).
static constexpr int B_ = 8;
static constexpr int S_ = 2048;
static constexpr int H_ = 768;            // 192 float4 chunks per row
static constexpr int TOKENS = B_ * S_;    // 16384
static constexpr float LN_EPS = 1e-12f;

typedef float nfloat4 __attribute__((ext_vector_type(4)));

__global__ __launch_bounds__(256, 4) void bert_emb_kernel(
    const int* __restrict__ word_ids,
    const int* __restrict__ modal_ids,
    const int* __restrict__ seg_ids,
    const int* __restrict__ npi_ids,
    const int* __restrict__ posi_ids,
    const float* __restrict__ age_tau,
    const float* __restrict__ delay_tau,
    const float* __restrict__ word_table,
    const float* __restrict__ modal_table,
    const float* __restrict__ seg_table,
    const float* __restrict__ npi_table,
    const float* __restrict__ posi_table,
    const float* __restrict__ age_w,      // [767]
    const float* __restrict__ age_b,      // [767]
    const float* __restrict__ age_w0,     // [1]
    const float* __restrict__ age_b0,     // [1]
    const float* __restrict__ delay_w,    // [767]
    const float* __restrict__ delay_b,    // [767]
    const float* __restrict__ delay_w0,   // [1]
    const float* __restrict__ delay_b0,   // [1]
    const float* __restrict__ ln_gamma,   // [768]
    const float* __restrict__ ln_beta,    // [768]
    float* __restrict__ out)
{
    const int wave = threadIdx.x >> 6;         // 0..3
    const int lane = threadIdx.x & 63;         // 0..63
    const int token = (blockIdx.x << 2) + wave;  // grid = TOKENS/4 exactly

    // Per-token scalars (broadcast loads within the wave)
    const int wid = word_ids[token];
    const int mid = modal_ids[token];
    const int sid = seg_ids[token];
    const int nid = npi_ids[token];
    const int pid = posi_ids[token];
    const float atau = age_tau[token];
    const float dtau = delay_tau[token];
    const float aw0 = age_w0[0], ab0 = age_b0[0];
    const float dw0 = delay_w0[0], db0 = delay_b0[0];

    const float4* wrow = reinterpret_cast<const float4*>(word_table  + (size_t)wid * H_);
    const float4* mrow = reinterpret_cast<const float4*>(modal_table + (size_t)mid * H_);
    const float4* srow = reinterpret_cast<const float4*>(seg_table   + (size_t)sid * H_);
    const float4* nrow = reinterpret_cast<const float4*>(npi_table   + (size_t)nid * H_);
    const float4* prow = reinterpret_cast<const float4*>(posi_table  + (size_t)pid * H_);
    const float4* awv = reinterpret_cast<const float4*>(age_w);
    const float4* abv = reinterpret_cast<const float4*>(age_b);
    const float4* dwv = reinterpret_cast<const float4*>(delay_w);
    const float4* dbv = reinterpret_cast<const float4*>(delay_b);

    float vals[12];
    float ssum = 0.0f, ssq = 0.0f;

#pragma unroll
    for (int c = 0; c < 3; ++c) {
        const int h4 = lane + (c << 6);        // 0..191 (chunk index)
        const float4 we = wrow[h4];
        const float4 me = mrow[h4];
        const float4 se = srow[h4];
        const float4 ne = nrow[h4];
        const float4 pe = prow[h4];

        float4 aw, ab, dw, db;
        if (h4 < (H_ / 4 - 1)) {               // chunks 0..190: fully inside [0,767)
            aw = awv[h4]; ab = abv[h4]; dw = dwv[h4]; db = dbv[h4];
        } else {                               // chunk 191 covers h=764..767; w/b have 767 elems
            aw = make_float4(age_w[764],   age_w[765],   age_w[766],   0.0f);
            ab = make_float4(age_b[764],   age_b[765],   age_b[766],   0.0f);
            dw = make_float4(delay_w[764], delay_w[765], delay_w[766], 0.0f);
            db = make_float4(delay_b[764], delay_b[765], delay_b[766], 0.0f);
        }

        float av0 = __sinf(atau * aw.x + ab.x);
        float av1 = __sinf(atau * aw.y + ab.y);
        float av2 = __sinf(atau * aw.z + ab.z);
        float av3 = __sinf(atau * aw.w + ab.w);
        float dv0 = __sinf(dtau * dw.x + db.x);
        float dv1 = __sinf(dtau * dw.y + db.y);
        float dv2 = __sinf(dtau * dw.z + db.z);
        float dv3 = __sinf(dtau * dw.w + db.w);
        if (h4 == (H_ / 4 - 1)) {              // h = 767: linear branch of time2vec
            av3 = atau * aw0 + ab0;
            dv3 = dtau * dw0 + db0;
        }

        const float e0 = we.x + me.x + se.x + ne.x + pe.x + av0 + dv0;
        const float e1 = we.y + me.y + se.y + ne.y + pe.y + av1 + dv1;
        const float e2 = we.z + me.z + se.z + ne.z + pe.z + av2 + dv2;
        const float e3 = we.w + me.w + se.w + ne.w + pe.w + av3 + dv3;

        vals[c * 4 + 0] = e0;
        vals[c * 4 + 1] = e1;
        vals[c * 4 + 2] = e2;
        vals[c * 4 + 3] = e3;
        ssum += e0 + e1 + e2 + e3;
        ssq  += e0 * e0 + e1 * e1 + e2 * e2 + e3 * e3;
    }

    // Wave-wide (64-lane) reduction for mean / variance
#pragma unroll
    for (int off = 32; off > 0; off >>= 1) {
        ssum += __shfl_down(ssum, off);
        ssq  += __shfl_down(ssq,  off);
    }
    ssum = __shfl(ssum, 0);
    ssq  = __shfl(ssq,  0);

    const float inv_h = 1.0f / (float)H_;
    const float mu = ssum * inv_h;
    const float var = ssq * inv_h - mu * mu;
    const float rstd = rsqrtf(var + LN_EPS);

    const float4* gv = reinterpret_cast<const float4*>(ln_gamma);
    const float4* bv = reinterpret_cast<const float4*>(ln_beta);
    nfloat4* orow = reinterpret_cast<nfloat4*>(out + (size_t)token * H_);

#pragma unroll
    for (int c = 0; c < 3; ++c) {
        const int h4 = lane + (c << 6);
        const float4 g  = gv[h4];
        const float4 bt = bv[h4];
        nfloat4 o;
        o.x = (vals[c * 4 + 0] - mu) * rstd * g.x + bt.x;
        o.y = (vals[c * 4 + 1] - mu) * rstd * g.y + bt.y;
        o.z = (vals[c * 4 + 2] - mu) * rstd * g.z + bt.z;
        o.w = (vals[c * 4 + 3] - mu) * rstd * g.w + bt.w;
        __builtin_nontemporal_store(o, &orow[h4]);
    }
}

extern "C" void kernel_launch(void* const* d_in, const int* in_sizes, int n_in,
                              void* d_out, int out_size, void* d_ws, size_t ws_size,
                              hipStream_t stream) {
    const int*   word_ids    = (const int*)  d_in[0];
    const int*   modal_ids   = (const int*)  d_in[1];
    const int*   seg_ids     = (const int*)  d_in[2];
    const int*   npi_ids     = (const int*)  d_in[3];
    const int*   posi_ids    = (const int*)  d_in[4];
    const float* age_tau     = (const float*)d_in[5];
    const float* delay_tau   = (const float*)d_in[6];
    const float* word_table  = (const float*)d_in[7];
    const float* modal_table = (const float*)d_in[8];
    const float* seg_table   = (const float*)d_in[9];
    const float* npi_table   = (const float*)d_in[10];
    const float* posi_table  = (const float*)d_in[11];
    const float* age_w       = (const float*)d_in[12];
    const float* age_b       = (const float*)d_in[13];
    const float* age_w0      = (const float*)d_in[14];
    const float* age_b0      = (const float*)d_in[15];
    const float* delay_w     = (const float*)d_in[16];
    const float* delay_b     = (const float*)d_in[17];
    const float* delay_w0    = (const float*)d_in[18];
    const float* delay_b0    = (const float*)d_in[19];
    const float* ln_gamma    = (const float*)d_in[20];
    const float* ln_beta     = (const float*)d_in[21];
    float* out = (float*)d_out;

    dim3 grid(TOKENS / 4);   // 4096 blocks, 4 tokens (waves) each
    dim3 block(256);
    hipLaunchKernelGGL(bert_emb_kernel, grid, block, 0, stream,
                       word_ids, modal_ids, seg_ids, npi_ids, posi_ids,
                       age_tau, delay_tau,
                       word_table, modal_table, seg_table, npi_table, posi_table,
                       age_w, age_b, age_w0, age_b0,
                       delay_w, delay_b, delay_w0, delay_b0,
                       ln_gamma, ln_beta, out);
}

// Round 5
// 233.260 us; speedup vs baseline: 1.3304x; 1.0152x over previous
//
#include <hip/hip_runtime.h>
#include <cmath>

// BertEmbeddings: B=8, S=2048, H=768. fp32 in/out.
// One 64-lane wave per token; 4 tokens per 256-thread block.
// R1 post-mortem: launch_bounds cap below natural VGPR need -> scratch spill
//   disaster (WRITE 49->246 MB). Tripwire: watch WRITE_SIZE.
// R3: __sinf + nt stores + (256,4): kernel ~50us, latency-bound at 4 w/SIMD.
// R5: stage token-invariant vectors (age_w/b, delay_w/b, gamma, beta, 18 KB)
//   in LDS -> removes 48 regs of in-flight param loads, lets all 15 row
//   gathers hoist into one vmcnt group; tighten to (256,5) = 102-reg cap.
static constexpr int B_ = 8;
static constexpr int S_ = 2048;
static constexpr int H_ = 768;            // 192 float4 chunks per row
static constexpr int TOKENS = B_ * S_;    // 16384
static constexpr float LN_EPS = 1e-12f;

typedef float nfloat4 __attribute__((ext_vector_type(4)));

__global__ __launch_bounds__(256, 5) void bert_emb_kernel(
    const int* __restrict__ word_ids,
    const int* __restrict__ modal_ids,
    const int* __restrict__ seg_ids,
    const int* __restrict__ npi_ids,
    const int* __restrict__ posi_ids,
    const float* __restrict__ age_tau,
    const float* __restrict__ delay_tau,
    const float* __restrict__ word_table,
    const float* __restrict__ modal_table,
    const float* __restrict__ seg_table,
    const float* __restrict__ npi_table,
    const float* __restrict__ posi_table,
    const float* __restrict__ age_w,      // [767]
    const float* __restrict__ age_b,      // [767]
    const float* __restrict__ age_w0,     // [1]
    const float* __restrict__ age_b0,     // [1]
    const float* __restrict__ delay_w,    // [767]
    const float* __restrict__ delay_b,    // [767]
    const float* __restrict__ delay_w0,   // [1]
    const float* __restrict__ delay_b0,   // [1]
    const float* __restrict__ ln_gamma,   // [768]
    const float* __restrict__ ln_beta,    // [768]
    float* __restrict__ out)
{
    __shared__ __align__(16) float s_aw[H_];
    __shared__ __align__(16) float s_ab[H_];
    __shared__ __align__(16) float s_dw[H_];
    __shared__ __align__(16) float s_db[H_];
    __shared__ __align__(16) float s_g [H_];
    __shared__ __align__(16) float s_bt[H_];

    // Cooperative stage of token-invariant vectors (pad element 767 with 0)
    for (int i = threadIdx.x; i < H_; i += 256) {
        const bool in = (i < H_ - 1);
        s_aw[i] = in ? age_w[i]   : 0.0f;
        s_ab[i] = in ? age_b[i]   : 0.0f;
        s_dw[i] = in ? delay_w[i] : 0.0f;
        s_db[i] = in ? delay_b[i] : 0.0f;
        s_g [i] = ln_gamma[i];
        s_bt[i] = ln_beta[i];
    }
    __syncthreads();

    const int wave = threadIdx.x >> 6;         // 0..3
    const int lane = threadIdx.x & 63;         // 0..63
    const int token = (blockIdx.x << 2) + wave;  // grid = TOKENS/4 exactly

    // Per-token scalars (broadcast loads within the wave)
    const int wid = word_ids[token];
    const int mid = modal_ids[token];
    const int sid = seg_ids[token];
    const int nid = npi_ids[token];
    const int pid = posi_ids[token];
    const float atau = age_tau[token];
    const float dtau = delay_tau[token];
    const float aw0 = age_w0[0], ab0 = age_b0[0];
    const float dw0 = delay_w0[0], db0 = delay_b0[0];

    const float4* wrow = reinterpret_cast<const float4*>(word_table  + (size_t)wid * H_);
    const float4* mrow = reinterpret_cast<const float4*>(modal_table + (size_t)mid * H_);
    const float4* srow = reinterpret_cast<const float4*>(seg_table   + (size_t)sid * H_);
    const float4* nrow = reinterpret_cast<const float4*>(npi_table   + (size_t)nid * H_);
    const float4* prow = reinterpret_cast<const float4*>(posi_table  + (size_t)pid * H_);
    const float4* awv = reinterpret_cast<const float4*>(s_aw);
    const float4* abv = reinterpret_cast<const float4*>(s_ab);
    const float4* dwv = reinterpret_cast<const float4*>(s_dw);
    const float4* dbv = reinterpret_cast<const float4*>(s_db);

    float vals[12];
    float ssum = 0.0f, ssq = 0.0f;

#pragma unroll
    for (int c = 0; c < 3; ++c) {
        const int h4 = lane + (c << 6);        // 0..191 (chunk index)
        const float4 we = wrow[h4];
        const float4 me = mrow[h4];
        const float4 se = srow[h4];
        const float4 ne = nrow[h4];
        const float4 pe = prow[h4];

        const float4 aw = awv[h4];
        const float4 ab = abv[h4];
        const float4 dw = dwv[h4];
        const float4 db = dbv[h4];

        float av0 = __sinf(atau * aw.x + ab.x);
        float av1 = __sinf(atau * aw.y + ab.y);
        float av2 = __sinf(atau * aw.z + ab.z);
        float av3 = __sinf(atau * aw.w + ab.w);
        float dv0 = __sinf(dtau * dw.x + db.x);
        float dv1 = __sinf(dtau * dw.y + db.y);
        float dv2 = __sinf(dtau * dw.z + db.z);
        float dv3 = __sinf(dtau * dw.w + db.w);
        if (h4 == (H_ / 4 - 1)) {              // h = 767: linear branch of time2vec
            av3 = atau * aw0 + ab0;
            dv3 = dtau * dw0 + db0;
        }

        const float e0 = we.x + me.x + se.x + ne.x + pe.x + av0 + dv0;
        const float e1 = we.y + me.y + se.y + ne.y + pe.y + av1 + dv1;
        const float e2 = we.z + me.z + se.z + ne.z + pe.z + av2 + dv2;
        const float e3 = we.w + me.w + se.w + ne.w + pe.w + av3 + dv3;

        vals[c * 4 + 0] = e0;
        vals[c * 4 + 1] = e1;
        vals[c * 4 + 2] = e2;
        vals[c * 4 + 3] = e3;
        ssum += e0 + e1 + e2 + e3;
        ssq  += e0 * e0 + e1 * e1 + e2 * e2 + e3 * e3;
    }

    // Wave-wide (64-lane) reduction for mean / variance
#pragma unroll
    for (int off = 32; off > 0; off >>= 1) {
        ssum += __shfl_down(ssum, off);
        ssq  += __shfl_down(ssq,  off);
    }
    ssum = __shfl(ssum, 0);
    ssq  = __shfl(ssq,  0);

    const float inv_h = 1.0f / (float)H_;
    const float mu = ssum * inv_h;
    const float var = ssq * inv_h - mu * mu;
    const float rstd = rsqrtf(var + LN_EPS);

    const float4* gv = reinterpret_cast<const float4*>(s_g);
    const float4* bv = reinterpret_cast<const float4*>(s_bt);
    nfloat4* orow = reinterpret_cast<nfloat4*>(out + (size_t)token * H_);

#pragma unroll
    for (int c = 0; c < 3; ++c) {
        const int h4 = lane + (c << 6);
        const float4 g  = gv[h4];
        const float4 bt = bv[h4];
        nfloat4 o;
        o.x = (vals[c * 4 + 0] - mu) * rstd * g.x + bt.x;
        o.y = (vals[c * 4 + 1] - mu) * rstd * g.y + bt.y;
        o.z = (vals[c * 4 + 2] - mu) * rstd * g.z + bt.z;
        o.w = (vals[c * 4 + 3] - mu) * rstd * g.w + bt.w;
        __builtin_nontemporal_store(o, &orow[h4]);
    }
}

extern "C" void kernel_launch(void* const* d_in, const int* in_sizes, int n_in,
                              void* d_out, int out_size, void* d_ws, size_t ws_size,
                              hipStream_t stream) {
    const int*   word_ids    = (const int*)  d_in[0];
    const int*   modal_ids   = (const int*)  d_in[1];
    const int*   seg_ids     = (const int*)  d_in[2];
    const int*   npi_ids     = (const int*)  d_in[3];
    const int*   posi_ids    = (const int*)  d_in[4];
    const float* age_tau     = (const float*)d_in[5];
    const float* delay_tau   = (const float*)d_in[6];
    const float* word_table  = (const float*)d_in[7];
    const float* modal_table = (const float*)d_in[8];
    const float* seg_table   = (const float*)d_in[9];
    const float* npi_table   = (const float*)d_in[10];
    const float* posi_table  = (const float*)d_in[11];
    const float* age_w       = (const float*)d_in[12];
    const float* age_b       = (const float*)d_in[13];
    const float* age_w0      = (const float*)d_in[14];
    const float* age_b0      = (const float*)d_in[15];
    const float* delay_w     = (const float*)d_in[16];
    const float* delay_b     = (const float*)d_in[17];
    const float* delay_w0    = (const float*)d_in[18];
    const float* delay_b0    = (const float*)d_in[19];
    const float* ln_gamma    = (const float*)d_in[20];
    const float* ln_beta     = (const float*)d_in[21];
    float* out = (float*)d_out;

    dim3 grid(TOKENS / 4);   // 4096 blocks, 4 tokens (waves) each
    dim3 block(256);
    hipLaunchKernelGGL(bert_emb_kernel, grid, block, 0, stream,
                       word_ids, modal_ids, seg_ids, npi_ids, posi_ids,
                       age_tau, delay_tau,
                       word_table, modal_table, seg_table, npi_table, posi_table,
                       age_w, age_b, age_w0, age_b0,
                       delay_w, delay_b, delay_w0, delay_b0,
                       ln_gamma, ln_beta, out);
}